// Round 8
// baseline (399.502 us; speedup 1.0000x reference)
//
#include <hip/hip_runtime.h>
#include <hip/hip_fp16.h>
#include <hip/hip_cooperative_groups.h>

namespace cg = cooperative_groups;

#define D 128
#define CHUNK 8192     // edges per partition block
#define BSH 7          // 128 nodes per bucket
#define BNODES 128
#define MAXNB 512      // supports n <= 65536
#define CAP 6144       // LDS CSR staging capacity (avg bucket ~1640 edges)
#define PADK 136       // LDS row stride in halves (+8 pad: 2-way bank aliasing only)

typedef _Float16 half8 __attribute__((ext_vector_type(8)));
typedef float float4v __attribute__((ext_vector_type(4)));

// ================= fused cooperative preprocessing =================
// phases: wprep -> bucket hist -> 3-phase exclusive scan -> partition scatter
//         -> per-bucket CSR build (+deg/dis).  One launch, grid.sync() between.
__global__ __launch_bounds__(256) void preproc(
    const int* __restrict__ src_n, const int* __restrict__ dst_n,
    const int* __restrict__ src_r, const int* __restrict__ dst_r,
    int En, int Er,
    const float* __restrict__ W2, const float* __restrict__ W1,
    _Float16* __restrict__ Wt2, _Float16* __restrict__ Wt1,
    int* __restrict__ base2, int* __restrict__ bsum2,
    unsigned int* __restrict__ part_n, unsigned int* __restrict__ part_r,
    int* __restrict__ rs2, float* __restrict__ dis2,
    unsigned short* __restrict__ csr_n, unsigned short* __restrict__ csr_r,
    int n, int NB, int NC, int L, int nb_scan)
{
    cg::grid_group grid = cg::this_grid();
    __shared__ __align__(16) char smem[14336];
    int t = threadIdx.x;
    int nblk = gridDim.x;  // 2*NC

    // ---- phase 0: weight transpose+cast (grid-strided, 32768 elems) ----
    for (int i = blockIdx.x * 256 + t; i < 2 * 128 * 128; i += nblk * 256) {
        int m = i >> 14, idx = i & 16383;
        int nn = idx >> 7, k = idx & 127;
        const float* W = m ? W1 : W2;
        _Float16* Wt = m ? Wt1 : Wt2;
        Wt[nn * 128 + k] = (_Float16)W[k * 128 + nn];
    }

    // ---- phase 1: per-(graph,chunk) bucket histogram ----
    {
        int g = blockIdx.x / NC, c = blockIdx.x % NC;
        int* hist = (int*)smem;
        const int* dst = g ? dst_r : dst_n;
        int E = g ? Er : En;
        for (int i = t; i < NB; i += 256) hist[i] = 0;
        __syncthreads();
        int e0 = c * CHUNK, e1 = min(e0 + CHUNK, E);
        for (int e = e0 + t; e < e1; e += 256)
            atomicAdd(&hist[dst[e] >> BSH], 1);
        __syncthreads();
        for (int b = t; b < NB; b += 256)
            base2[g * L + b * NC + c] = hist[b];  // bucket-major
    }
    grid.sync();

    // ---- phase 2a: per-1024-chunk sums (256 thr x 4 elems) ----
    for (int task = blockIdx.x; task < 2 * nb_scan; task += nblk) {
        int g = task / nb_scan, b = task % nb_scan;
        int base = b * 1024 + t * 4;
        int s = 0;
        #pragma unroll
        for (int j = 0; j < 4; ++j) {
            int i = base + j;
            if (i < L) s += base2[g * L + i];
        }
        int lane = t & 63, wid = t >> 6;
        #pragma unroll
        for (int off = 32; off; off >>= 1) s += __shfl_down(s, off, 64);
        int* wsum = (int*)smem;
        if (lane == 0) wsum[wid] = s;
        __syncthreads();
        if (t == 0) {
            int tot = 0;
            for (int w = 0; w < 4; ++w) tot += wsum[w];
            bsum2[g * 64 + b] = tot;
        }
        __syncthreads();
    }
    grid.sync();

    // ---- phase 2b: exclusive-scan the <=64 chunk sums per graph ----
    if (blockIdx.x == 0 && t < 128) {
        int wid = t >> 6, lane = t & 63;
        int v = (lane < nb_scan) ? bsum2[wid * 64 + lane] : 0;
        int incl = v;
        #pragma unroll
        for (int off = 1; off < 64; off <<= 1) {
            int tt = __shfl_up(incl, off, 64);
            if (lane >= off) incl += tt;
        }
        if (lane < nb_scan) bsum2[wid * 64 + lane] = incl - v;
    }
    grid.sync();

    // ---- phase 2c: full exclusive scan of base2 in place ----
    for (int task = blockIdx.x; task < 2 * nb_scan; task += nblk) {
        int g = task / nb_scan, b = task % nb_scan;
        int base = b * 1024 + t * 4;
        int v[4];
        #pragma unroll
        for (int j = 0; j < 4; ++j) {
            int i = base + j;
            v[j] = (i < L) ? base2[g * L + i] : 0;
        }
        int tsum = v[0] + v[1] + v[2] + v[3];
        int lane = t & 63, wid = t >> 6;
        int incl = tsum;
        #pragma unroll
        for (int off = 1; off < 64; off <<= 1) {
            int tt = __shfl_up(incl, off, 64);
            if (lane >= off) incl += tt;
        }
        int* wsum = (int*)smem;
        if (lane == 63) wsum[wid] = incl;
        __syncthreads();
        if (t == 0) {
            int s = 0;
            for (int w = 0; w < 4; ++w) { int tt = wsum[w]; wsum[w] = s; s += tt; }
        }
        __syncthreads();
        int excl = incl - tsum + wsum[wid] + bsum2[g * 64 + b];
        #pragma unroll
        for (int j = 0; j < 4; ++j) {
            int i = base + j;
            if (i < L) base2[g * L + i] = excl;
            excl += v[j];
        }
        __syncthreads();
    }
    grid.sync();

    // ---- phase 3: partition edges into bucket-contiguous runs ----
    {
        int g = blockIdx.x / NC, c = blockIdx.x % NC;
        const int* src = g ? src_r : src_n;
        const int* dst = g ? dst_r : dst_n;
        unsigned int* part = g ? part_r : part_n;
        int E = g ? Er : En;
        int* cur = (int*)smem;
        for (int b = t; b < NB; b += 256)
            cur[b] = base2[g * L + b * NC + c];
        __syncthreads();
        int e0 = c * CHUNK, e1 = min(e0 + CHUNK, E);
        for (int e = e0 + t; e < e1; e += 256) {
            int d = dst[e];
            int pos = atomicAdd(&cur[d >> BSH], 1);
            part[pos] = ((unsigned)d << 16) | (unsigned)src[e];
        }
    }
    grid.sync();

    // ---- phase 4: per-bucket CSR build + deg/dis (grid-strided tasks) ----
    {
        int* deg = (int*)smem;                     // 128 ints
        int* cur = deg + 128;                      // 128 ints
        int* w0tot = cur + 128;                    // 1 int (+pad)
        unsigned short* buf = (unsigned short*)(w0tot + 4);  // CAP ushorts
        for (int task = blockIdx.x; task < 2 * NB; task += nblk) {
            int g = task / NB, b = task % NB;
            const unsigned int* part = g ? part_r : part_n;
            unsigned short* csr = g ? csr_r : csr_n;
            int E = g ? Er : En;
            if (t < BNODES) deg[t] = 0;
            __syncthreads();
            int bstart = base2[g * L + b * NC];
            int bend = (b + 1 < NB) ? base2[g * L + (b + 1) * NC] : E;
            int sz = bend - bstart;
            for (int e = bstart + t; e < bend; e += 256)
                atomicAdd(&deg[(part[e] >> 16) & (BNODES - 1)], 1);
            __syncthreads();
            int incl = 0, v = 0;
            if (t < BNODES) {
                int lane = t & 63;
                v = deg[t];
                incl = v;
                #pragma unroll
                for (int off = 1; off < 64; off <<= 1) {
                    int tt = __shfl_up(incl, off, 64);
                    if (lane >= off) incl += tt;
                }
                if (t == 63) w0tot[0] = incl;
            }
            __syncthreads();
            if (t < BNODES) {
                int excl = incl - v + ((t >= 64) ? w0tot[0] : 0);
                cur[t] = excl;
                int idx = b * BNODES + t;
                if (idx < n) {
                    rs2[g * (n + 1) + idx] = bstart + excl;
                    dis2[g * n + idx] = rsqrtf((float)(deg[t] + 1));
                }
            }
            if (b == NB - 1 && t == 255) rs2[g * (n + 1) + n] = E;
            __syncthreads();
            if (sz <= CAP) {
                for (int e = bstart + t; e < bend; e += 256) {
                    unsigned int p = part[e];
                    int pos = atomicAdd(&cur[(p >> 16) & (BNODES - 1)], 1);
                    buf[pos] = (unsigned short)(p & 0xffffu);
                }
                __syncthreads();
                for (int i = t; i < sz; i += 256) csr[bstart + i] = buf[i];  // coalesced
            } else {  // oversized bucket fallback
                for (int e = bstart + t; e < bend; e += 256) {
                    unsigned int p = part[e];
                    int pos = atomicAdd(&cur[(p >> 16) & (BNODES - 1)], 1);
                    csr[bstart + pos] = (unsigned short)(p & 0xffffu);
                }
            }
            __syncthreads();
        }
    }
}

// ---------------- per-layer kernels (unchanged from R7) ----------------

// Layer-1: Y[v,:] = (half) dis[v] * (X[v,:] @ W).  fp32 vector math (x stays exact).
__global__ __launch_bounds__(256) void gemm_scale(const float* __restrict__ X,
                                                  const float* __restrict__ W,
                                                  const float* __restrict__ dis,
                                                  __half* __restrict__ Y, int n) {
    __shared__ float sX[128 * D];
    int t = threadIdx.x;
    int rg = t >> 4;
    int cg = (t & 15) << 3;
    int rb = blockIdx.x * 128;
    int rows = min(128, n - rb);

    float4* sX4 = (float4*)sX;
    for (int i = t; i < rows * 32; i += 256)
        sX4[i] = ((const float4*)X)[(size_t)rb * 32 + i];
    __syncthreads();

    float acc[8][8] = {};
    #pragma unroll 2
    for (int k0 = 0; k0 < D; k0 += 4) {
        float4 xr[8];
        #pragma unroll
        for (int r = 0; r < 8; ++r)
            xr[r] = *(const float4*)&sX[(rg * 8 + r) * D + k0];
        #pragma unroll
        for (int j = 0; j < 4; ++j) {
            float4 wa = *(const float4*)(W + (size_t)(k0 + j) * D + cg);
            float4 wb = *(const float4*)(W + (size_t)(k0 + j) * D + cg + 4);
            #pragma unroll
            for (int r = 0; r < 8; ++r) {
                float xv = ((const float*)&xr[r])[j];
                acc[r][0] += xv * wa.x; acc[r][1] += xv * wa.y;
                acc[r][2] += xv * wa.z; acc[r][3] += xv * wa.w;
                acc[r][4] += xv * wb.x; acc[r][5] += xv * wb.y;
                acc[r][6] += xv * wb.z; acc[r][7] += xv * wb.w;
            }
        }
    }
    #pragma unroll
    for (int r = 0; r < 8; ++r) {
        int row = rb + rg * 8 + r;
        if (row < n) {
            float dv = dis[row];
            __half2 p0 = __floats2half2_rn(acc[r][0] * dv, acc[r][1] * dv);
            __half2 p1 = __floats2half2_rn(acc[r][2] * dv, acc[r][3] * dv);
            __half2 p2 = __floats2half2_rn(acc[r][4] * dv, acc[r][5] * dv);
            __half2 p3 = __floats2half2_rn(acc[r][6] * dv, acc[r][7] * dv);
            uint4 o;
            o.x = *(unsigned*)&p0; o.y = *(unsigned*)&p1;
            o.z = *(unsigned*)&p2; o.w = *(unsigned*)&p3;
            *(uint4*)(Y + (size_t)row * D + cg) = o;  // 16B coalesced
        }
    }
}

// Layers 2,3: Y[v,:] = (half) dis[v] * (Xh[v,:] @ W), Xh fp16, MFMA 16x16x32 f16.
__global__ __launch_bounds__(256) void gemm_mfma(const _Float16* __restrict__ Xh,
                                                 const _Float16* __restrict__ Wt,  // [n][k]
                                                 const float* __restrict__ dis,
                                                 _Float16* __restrict__ Y, int n) {
    __shared__ _Float16 sA[128 * PADK];
    __shared__ _Float16 sB[128 * PADK];
    int t = threadIdx.x;
    int rb = blockIdx.x * 128;
    int rows = min(128, n - rb);

    for (int i = t; i < 128 * 16; i += 256) {        // B: 128 rows x 16 segs of 8 halves
        int r = i >> 4, s = i & 15;
        *(uint4*)&sB[r * PADK + s * 8] = ((const uint4*)Wt)[i];
    }
    for (int i = t; i < rows * 16; i += 256) {
        int r = i >> 4, s = i & 15;
        *(uint4*)&sA[r * PADK + s * 8] = ((const uint4*)(Xh + (size_t)rb * D))[i];
    }
    if (rows < 128) {
        for (int i = rows * 16 + t; i < 128 * 16; i += 256) {
            int r = i >> 4, s = i & 15;
            *(uint4*)&sA[r * PADK + s * 8] = make_uint4(0, 0, 0, 0);
        }
    }
    __syncthreads();

    int w = t >> 6, lane = t & 63;
    int quad = lane >> 4, l16 = lane & 15;
    float4v acc[2][8];
    #pragma unroll
    for (int rt = 0; rt < 2; ++rt)
        #pragma unroll
        for (int ct = 0; ct < 8; ++ct)
            acc[rt][ct] = (float4v){0.f, 0.f, 0.f, 0.f};

    #pragma unroll
    for (int k0 = 0; k0 < 128; k0 += 32) {
        half8 a0 = *(half8*)&sA[(w * 32 + l16) * PADK + k0 + quad * 8];
        half8 a1 = *(half8*)&sA[(w * 32 + 16 + l16) * PADK + k0 + quad * 8];
        #pragma unroll
        for (int ct = 0; ct < 8; ++ct) {
            half8 b = *(half8*)&sB[(ct * 16 + l16) * PADK + k0 + quad * 8];
            acc[0][ct] = __builtin_amdgcn_mfma_f32_16x16x32_f16(a0, b, acc[0][ct], 0, 0, 0);
            acc[1][ct] = __builtin_amdgcn_mfma_f32_16x16x32_f16(a1, b, acc[1][ct], 0, 0, 0);
        }
    }
    // C/D: col = l16, row = quad*4 + r
    #pragma unroll
    for (int rt = 0; rt < 2; ++rt) {
        #pragma unroll
        for (int r = 0; r < 4; ++r) {
            int row = rb + w * 32 + rt * 16 + quad * 4 + r;
            if (row < n) {
                float dv = dis[row];
                #pragma unroll
                for (int ct = 0; ct < 8; ++ct)
                    Y[(size_t)row * D + ct * 16 + l16] = (_Float16)(acc[rt][ct][r] * dv);
            }
        }
    }
}

// out[v,:] = maybe_relu( dis[v] * (sum_e g[src_e,:] + g[v,:]) + bias )
// g fp16; one node per quarter-wave (16 lanes x uint4 = 256B row).
__global__ __launch_bounds__(256) void aggregate(const __half* __restrict__ g,
                                                 const int* __restrict__ rs,
                                                 const unsigned short* __restrict__ csr,
                                                 const float* __restrict__ dis,
                                                 const float* __restrict__ bias,
                                                 float* __restrict__ outf,
                                                 _Float16* __restrict__ outh,
                                                 int n, int do_relu, int write_half) {
    int v = blockIdx.x * 16 + (threadIdx.x >> 4);
    if (v >= n) return;
    int l16 = threadIdx.x & 15;
    const uint4* g4 = (const uint4*)g;  // 16 uint4 per row
    float acc[8];
    {
        uint4 raw = g4[(size_t)v * 16 + l16];  // self loop (g pre-scaled by dis)
        float2 f0 = __half22float2(*(__half2*)&raw.x);
        float2 f1 = __half22float2(*(__half2*)&raw.y);
        float2 f2 = __half22float2(*(__half2*)&raw.z);
        float2 f3 = __half22float2(*(__half2*)&raw.w);
        acc[0] = f0.x; acc[1] = f0.y; acc[2] = f1.x; acc[3] = f1.y;
        acc[4] = f2.x; acc[5] = f2.y; acc[6] = f3.x; acc[7] = f3.y;
    }
    int e = rs[v], end = rs[v + 1];
    while (e < end) {
        int m = min(16, end - e);
        int sid = (e + l16 < end) ? (int)csr[e + l16] : 0;
        int j = 0;
        for (; j + 7 < m; j += 8) {
            uint4 raw[8];
            #pragma unroll
            for (int u = 0; u < 8; ++u) {
                int s = __shfl(sid, j + u, 16);
                raw[u] = g4[(size_t)s * 16 + l16];
            }
            #pragma unroll
            for (int u = 0; u < 8; ++u) {
                float2 f0 = __half22float2(*(__half2*)&raw[u].x);
                float2 f1 = __half22float2(*(__half2*)&raw[u].y);
                float2 f2 = __half22float2(*(__half2*)&raw[u].z);
                float2 f3 = __half22float2(*(__half2*)&raw[u].w);
                acc[0] += f0.x; acc[1] += f0.y; acc[2] += f1.x; acc[3] += f1.y;
                acc[4] += f2.x; acc[5] += f2.y; acc[6] += f3.x; acc[7] += f3.y;
            }
        }
        for (; j + 3 < m; j += 4) {
            uint4 raw[4];
            #pragma unroll
            for (int u = 0; u < 4; ++u) {
                int s = __shfl(sid, j + u, 16);
                raw[u] = g4[(size_t)s * 16 + l16];
            }
            #pragma unroll
            for (int u = 0; u < 4; ++u) {
                float2 f0 = __half22float2(*(__half2*)&raw[u].x);
                float2 f1 = __half22float2(*(__half2*)&raw[u].y);
                float2 f2 = __half22float2(*(__half2*)&raw[u].z);
                float2 f3 = __half22float2(*(__half2*)&raw[u].w);
                acc[0] += f0.x; acc[1] += f0.y; acc[2] += f1.x; acc[3] += f1.y;
                acc[4] += f2.x; acc[5] += f2.y; acc[6] += f3.x; acc[7] += f3.y;
            }
        }
        for (; j < m; ++j) {
            int s = __shfl(sid, j, 16);
            uint4 raw = g4[(size_t)s * 16 + l16];
            float2 f0 = __half22float2(*(__half2*)&raw.x);
            float2 f1 = __half22float2(*(__half2*)&raw.y);
            float2 f2 = __half22float2(*(__half2*)&raw.z);
            float2 f3 = __half22float2(*(__half2*)&raw.w);
            acc[0] += f0.x; acc[1] += f0.y; acc[2] += f1.x; acc[3] += f1.y;
            acc[4] += f2.x; acc[5] += f2.y; acc[6] += f3.x; acc[7] += f3.y;
        }
        e += m;
    }
    float dv = dis[v];
    const float4* b4 = (const float4*)bias;
    float4 ba = b4[2 * l16], bb = b4[2 * l16 + 1];
    float o[8];
    o[0] = dv * acc[0] + ba.x; o[1] = dv * acc[1] + ba.y;
    o[2] = dv * acc[2] + ba.z; o[3] = dv * acc[3] + ba.w;
    o[4] = dv * acc[4] + bb.x; o[5] = dv * acc[5] + bb.y;
    o[6] = dv * acc[6] + bb.z; o[7] = dv * acc[7] + bb.w;
    if (do_relu) {
        #pragma unroll
        for (int i = 0; i < 8; ++i) o[i] = fmaxf(o[i], 0.f);
    }
    if (write_half) {
        __half2 p0 = __floats2half2_rn(o[0], o[1]);
        __half2 p1 = __floats2half2_rn(o[2], o[3]);
        __half2 p2 = __floats2half2_rn(o[4], o[5]);
        __half2 p3 = __floats2half2_rn(o[6], o[7]);
        uint4 pk;
        pk.x = *(unsigned*)&p0; pk.y = *(unsigned*)&p1;
        pk.z = *(unsigned*)&p2; pk.w = *(unsigned*)&p3;
        ((uint4*)outh)[(size_t)v * 16 + l16] = pk;
    } else {
        float4* orow = (float4*)(outf + (size_t)v * D);
        orow[2 * l16] = make_float4(o[0], o[1], o[2], o[3]);
        orow[2 * l16 + 1] = make_float4(o[4], o[5], o[6], o[7]);
    }
}

// ---------------- host launcher ----------------

extern "C" void kernel_launch(void* const* d_in, const int* in_sizes, int n_in,
                              void* d_out, int out_size, void* d_ws, size_t ws_size,
                              hipStream_t stream) {
    const float* x      = (const float*)d_in[0];
    const float* W_role = (const float*)d_in[1];
    const float* b_role = (const float*)d_in[2];
    const float* W2     = (const float*)d_in[3];
    const float* b2     = (const float*)d_in[4];
    const float* W1     = (const float*)d_in[5];
    const float* b1     = (const float*)d_in[6];
    const int*   ein    = (const int*)d_in[7];
    const int*   eir    = (const int*)d_in[8];

    int n  = in_sizes[0] / D;   // 50000
    int En = in_sizes[7] / 2;   // 640000
    int Er = in_sizes[8] / 2;   // 640000
    const int* src_n = ein;
    const int* dst_n = ein + En;
    const int* src_r = eir;
    const int* dst_r = eir + Er;
    float* out = (float*)d_out;

    int NB = (n + BNODES - 1) >> BSH;                    // 391 buckets/graph
    int Emax = En > Er ? En : Er;
    int NC = (Emax + CHUNK - 1) / CHUNK;                 // 79 chunks/graph
    int L  = NB * NC;                                    // 30889 (must be <= 65536)
    int nb_scan = (L + 1023) / 1024;                     // 31 (must be <= 64)

    char* p = (char*)d_ws;
    auto alloc = [&](size_t bytes) { char* r = p; p += (bytes + 255) & ~(size_t)255; return r; };
    __half*         gbuf   = (__half*)alloc((size_t)n * D * sizeof(__half));      // 12.8 MB
    _Float16*       hbuf   = (_Float16*)alloc((size_t)n * D * sizeof(_Float16));  // 12.8 MB
    _Float16*       Wt2    = (_Float16*)alloc((size_t)D * D * sizeof(_Float16));
    _Float16*       Wt1    = (_Float16*)alloc((size_t)D * D * sizeof(_Float16));
    float*          dis2   = (float*)alloc((size_t)2 * n * sizeof(float));
    int*            rs2    = (int*)alloc((size_t)2 * (n + 1) * sizeof(int));
    int*            base2  = (int*)alloc((size_t)2 * L * sizeof(int));
    int*            bsum2  = (int*)alloc(512);
    unsigned int*   part_n = (unsigned int*)alloc((size_t)En * sizeof(unsigned int));
    unsigned int*   part_r = (unsigned int*)alloc((size_t)Er * sizeof(unsigned int));
    unsigned short* csr    = (unsigned short*)alloc((size_t)(En + Er) * sizeof(unsigned short));
    float* dis_n = dis2;
    float* dis_r = dis2 + n;
    int*   rs_n  = rs2;
    int*   rs_r  = rs2 + (n + 1);
    unsigned short* csr_n = csr;
    unsigned short* csr_r = csr + En;

    // ---- fused cooperative preprocessing (1 launch replaces 7) ----
    {
        void* args[] = {
            (void*)&src_n, (void*)&dst_n, (void*)&src_r, (void*)&dst_r,
            (void*)&En, (void*)&Er,
            (void*)&W2, (void*)&W1, (void*)&Wt2, (void*)&Wt1,
            (void*)&base2, (void*)&bsum2,
            (void*)&part_n, (void*)&part_r,
            (void*)&rs2, (void*)&dis2,
            (void*)&csr_n, (void*)&csr_r,
            (void*)&n, (void*)&NB, (void*)&NC, (void*)&L, (void*)&nb_scan
        };
        hipLaunchCooperativeKernel((const void*)preproc, dim3(2 * NC), dim3(256),
                                   args, 0, stream);
    }

    // ---- 3 GCN layers ----
    int gblk = (n + 127) / 128;
    int ablk = (n + 15) / 16;
    // layer 1: role graph; fp32 vector GEMM (x exact) -> fp16 g; aggregate -> fp16 h
    gemm_scale<<<gblk, 256, 0, stream>>>(x, W_role, dis_r, gbuf, n);
    aggregate<<<ablk, 256, 0, stream>>>(gbuf, rs_r, csr_r, dis_r, b_role,
                                        nullptr, hbuf, n, 1, 1);
    // layer 2: normal graph; MFMA GEMM (fp16 in/out); aggregate -> fp16 h
    gemm_mfma<<<gblk, 256, 0, stream>>>(hbuf, Wt2, dis_n, (_Float16*)gbuf, n);
    aggregate<<<ablk, 256, 0, stream>>>(gbuf, rs_n, csr_n, dis_n, b2,
                                        nullptr, hbuf, n, 1, 1);
    // layer 3: normal graph; MFMA GEMM; aggregate -> fp32 d_out
    gemm_mfma<<<gblk, 256, 0, stream>>>(hbuf, Wt1, dis_n, (_Float16*)gbuf, n);
    aggregate<<<ablk, 256, 0, stream>>>(gbuf, rs_n, csr_n, dis_n, b1,
                                        out, nullptr, n, 0, 0);
}

// Round 9
// 240.294 us; speedup vs baseline: 1.6626x; 1.6626x over previous
//
#include <hip/hip_runtime.h>
#include <hip/hip_fp16.h>

#define D 128
#define CHUNK 4096     // edges per partition block (4096: 314 blocks, better CU coverage)
#define BSH 7          // 128 nodes per bucket
#define BNODES 128
#define MAXNB 512      // supports n <= 65536
#define CAP 6144       // LDS CSR staging capacity (avg bucket ~1640 edges)
#define PADK 136       // LDS row stride in halves (+8 pad: 2-way bank aliasing only)

typedef _Float16 half8 __attribute__((ext_vector_type(8)));
typedef float float4v __attribute__((ext_vector_type(4)));

// ---------------- P1: weight prep (grid-strided) + per-(graph,chunk) bucket histogram ----------------
__global__ __launch_bounds__(256) void p1_hist(const int* __restrict__ dst_n,
                                               const int* __restrict__ dst_r,
                                               int En, int Er,
                                               const float* __restrict__ Wr,
                                               const float* __restrict__ W2,
                                               const float* __restrict__ W1,
                                               _Float16* __restrict__ Wtr,
                                               _Float16* __restrict__ Wt2,
                                               _Float16* __restrict__ Wt1,
                                               int* __restrict__ base2,
                                               int NB, int NC, int L) {
    // weight transpose+cast: Wt[m][n][k] = (half)W[m][k][n], m in {role,2,1}
    for (int i = blockIdx.x * 256 + threadIdx.x; i < 3 * 128 * 128; i += gridDim.x * 256) {
        int m = i >> 14, idx = i & 16383;
        int nn = idx >> 7, k = idx & 127;
        const float* W = (m == 0) ? Wr : (m == 1) ? W2 : W1;
        _Float16* Wt = (m == 0) ? Wtr : (m == 1) ? Wt2 : Wt1;
        Wt[nn * 128 + k] = (_Float16)W[k * 128 + nn];
    }
    int g = blockIdx.x / NC, c = blockIdx.x % NC;
    const int* dst = g ? dst_r : dst_n;
    int E = g ? Er : En;
    __shared__ int hist[MAXNB];
    for (int i = threadIdx.x; i < NB; i += 256) hist[i] = 0;
    __syncthreads();
    int e0 = c * CHUNK, e1 = min(e0 + CHUNK, E);
    for (int e = e0 + threadIdx.x; e < e1; e += 256)
        atomicAdd(&hist[dst[e] >> BSH], 1);
    __syncthreads();
    for (int b = threadIdx.x; b < NB; b += 256)
        base2[g * L + b * NC + c] = hist[b];  // bucket-major for stable partition scan
}

// ---------------- scan pass 1: per-1024-chunk sums ----------------
__global__ __launch_bounds__(1024) void scan_pass1(const int* __restrict__ data,
                                                   int* __restrict__ bsum2, int L, int nb) {
    int g = blockIdx.x / nb, b = blockIdx.x % nb;
    int i = b * 1024 + threadIdx.x;
    int v = (i < L) ? data[g * L + i] : 0;
    #pragma unroll
    for (int off = 32; off; off >>= 1) v += __shfl_down(v, off, 64);
    __shared__ int wsum[16];
    int lane = threadIdx.x & 63, wid = threadIdx.x >> 6;
    if (lane == 0) wsum[wid] = v;
    __syncthreads();
    if (threadIdx.x == 0) {
        int s = 0;
        for (int w = 0; w < 16; ++w) s += wsum[w];
        bsum2[g * 64 + b] = s;
    }
}

// ---------------- scan pass 3: full exclusive scan (inlines the bsum scan) ----------------
__global__ __launch_bounds__(1024) void scan_pass3(int* __restrict__ data,
                                                   const int* __restrict__ bsum2,
                                                   int L, int nb) {
    int g = blockIdx.x / nb, b = blockIdx.x % nb;
    __shared__ int sOffset;
    // wave 0 recomputes the exclusive scan of the <=64 chunk sums (replaces scan_pass2 dispatch)
    if (threadIdx.x < 64) {
        int lane = threadIdx.x;
        int v = (lane < nb) ? bsum2[g * 64 + lane] : 0;
        int incl = v;
        #pragma unroll
        for (int off = 1; off < 64; off <<= 1) {
            int t = __shfl_up(incl, off, 64);
            if (lane >= off) incl += t;
        }
        if (lane == b) sOffset = incl - v;
    }
    int i = b * 1024 + threadIdx.x;
    int v = (i < L) ? data[g * L + i] : 0;
    int lane = threadIdx.x & 63, wid = threadIdx.x >> 6;
    int incl = v;
    #pragma unroll
    for (int off = 1; off < 64; off <<= 1) {
        int t = __shfl_up(incl, off, 64);
        if (lane >= off) incl += t;
    }
    __shared__ int wsum[16];
    if (lane == 63) wsum[wid] = incl;
    __syncthreads();
    if (threadIdx.x == 0) {
        int s = 0;
        for (int w = 0; w < 16; ++w) { int t = wsum[w]; wsum[w] = s; s += t; }
    }
    __syncthreads();
    if (i < L) data[g * L + i] = incl - v + wsum[wid] + sOffset;
}

// ---------------- P2: partition edges into bucket-contiguous runs ----------------
// part entry = (dst<<16) | src   (requires n <= 65536)
__global__ __launch_bounds__(256) void p2_scatter(const int* __restrict__ src_n,
                                                  const int* __restrict__ dst_n,
                                                  const int* __restrict__ src_r,
                                                  const int* __restrict__ dst_r,
                                                  int En, int Er,
                                                  const int* __restrict__ base2,
                                                  unsigned int* __restrict__ part_n,
                                                  unsigned int* __restrict__ part_r,
                                                  int NB, int NC, int L) {
    int g = blockIdx.x / NC, c = blockIdx.x % NC;
    const int* src = g ? src_r : src_n;
    const int* dst = g ? dst_r : dst_n;
    unsigned int* part = g ? part_r : part_n;
    int E = g ? Er : En;
    __shared__ int cur[MAXNB];
    for (int b = threadIdx.x; b < NB; b += 256)
        cur[b] = base2[g * L + b * NC + c];
    __syncthreads();
    int e0 = c * CHUNK, e1 = min(e0 + CHUNK, E);
    for (int e = e0 + threadIdx.x; e < e1; e += 256) {
        int d = dst[e];
        int pos = atomicAdd(&cur[d >> BSH], 1);
        part[pos] = ((unsigned)d << 16) | (unsigned)src[e];
    }
}

// ---------------- P3: per-bucket CSR build (all-LDS) + deg/dis ----------------
__global__ __launch_bounds__(256) void p3_csr(const unsigned int* __restrict__ part_n,
                                              const unsigned int* __restrict__ part_r,
                                              const int* __restrict__ base2,
                                              int* __restrict__ rs2,
                                              float* __restrict__ dis2,
                                              unsigned short* __restrict__ csr_n,
                                              unsigned short* __restrict__ csr_r,
                                              int n, int NB, int NC, int L, int En, int Er) {
    int g = blockIdx.x / NB, b = blockIdx.x % NB;
    const unsigned int* part = g ? part_r : part_n;
    unsigned short* csr = g ? csr_r : csr_n;
    int E = g ? Er : En;
    __shared__ int deg[BNODES];
    __shared__ int cur[BNODES];
    __shared__ unsigned short buf[CAP];
    __shared__ int w0tot;
    int t = threadIdx.x;
    if (t < BNODES) deg[t] = 0;
    __syncthreads();
    int bstart = base2[g * L + b * NC];
    int bend = (b + 1 < NB) ? base2[g * L + (b + 1) * NC] : E;
    int sz = bend - bstart;
    for (int e = bstart + t; e < bend; e += 256)
        atomicAdd(&deg[(part[e] >> 16) & (BNODES - 1)], 1);
    __syncthreads();
    int incl = 0, v = 0;
    if (t < BNODES) {  // waves 0,1 fully active: safe shfl scan
        int lane = t & 63;
        v = deg[t];
        incl = v;
        #pragma unroll
        for (int off = 1; off < 64; off <<= 1) {
            int tt = __shfl_up(incl, off, 64);
            if (lane >= off) incl += tt;
        }
        if (t == 63) w0tot = incl;
    }
    __syncthreads();
    if (t < BNODES) {
        int excl = incl - v + ((t >= 64) ? w0tot : 0);
        cur[t] = excl;
        int idx = b * BNODES + t;
        if (idx < n) {
            rs2[g * (n + 1) + idx] = bstart + excl;
            dis2[g * n + idx] = rsqrtf((float)(deg[t] + 1));
        }
    }
    if (b == NB - 1 && t == 255) rs2[g * (n + 1) + n] = E;
    __syncthreads();
    if (sz <= CAP) {
        for (int e = bstart + t; e < bend; e += 256) {
            unsigned int p = part[e];
            int pos = atomicAdd(&cur[(p >> 16) & (BNODES - 1)], 1);
            buf[pos] = (unsigned short)(p & 0xffffu);
        }
        __syncthreads();
        for (int i = t; i < sz; i += 256) csr[bstart + i] = buf[i];  // coalesced
    } else {  // oversized bucket fallback (never hit at this scale)
        for (int e = bstart + t; e < bend; e += 256) {
            unsigned int p = part[e];
            int pos = atomicAdd(&cur[(p >> 16) & (BNODES - 1)], 1);
            csr[bstart + pos] = (unsigned short)(p & 0xffffu);
        }
    }
}

// ---------------- per-layer kernels ----------------

// MFMA GEMM core: Y[v,:] = (half) dis[v] * (A @ Wt^T) where sA is staged by caller-specific loader.
// Layers 2,3: fp16 input rows.
__global__ __launch_bounds__(256) void gemm_mfma(const _Float16* __restrict__ Xh,
                                                 const _Float16* __restrict__ Wt,  // [n][k]
                                                 const float* __restrict__ dis,
                                                 _Float16* __restrict__ Y, int n) {
    __shared__ _Float16 sA[128 * PADK];
    __shared__ _Float16 sB[128 * PADK];
    int t = threadIdx.x;
    int rb = blockIdx.x * 128;
    int rows = min(128, n - rb);

    for (int i = t; i < 128 * 16; i += 256) {
        int r = i >> 4, s = i & 15;
        *(uint4*)&sB[r * PADK + s * 8] = ((const uint4*)Wt)[i];
    }
    for (int i = t; i < rows * 16; i += 256) {
        int r = i >> 4, s = i & 15;
        *(uint4*)&sA[r * PADK + s * 8] = ((const uint4*)(Xh + (size_t)rb * D))[i];
    }
    if (rows < 128) {
        for (int i = rows * 16 + t; i < 128 * 16; i += 256) {
            int r = i >> 4, s = i & 15;
            *(uint4*)&sA[r * PADK + s * 8] = make_uint4(0, 0, 0, 0);
        }
    }
    __syncthreads();

    int w = t >> 6, lane = t & 63;
    int quad = lane >> 4, l16 = lane & 15;
    float4v acc[2][8];
    #pragma unroll
    for (int rt = 0; rt < 2; ++rt)
        #pragma unroll
        for (int ct = 0; ct < 8; ++ct)
            acc[rt][ct] = (float4v){0.f, 0.f, 0.f, 0.f};

    #pragma unroll
    for (int k0 = 0; k0 < 128; k0 += 32) {
        half8 a0 = *(half8*)&sA[(w * 32 + l16) * PADK + k0 + quad * 8];
        half8 a1 = *(half8*)&sA[(w * 32 + 16 + l16) * PADK + k0 + quad * 8];
        #pragma unroll
        for (int ct = 0; ct < 8; ++ct) {
            half8 b = *(half8*)&sB[(ct * 16 + l16) * PADK + k0 + quad * 8];
            acc[0][ct] = __builtin_amdgcn_mfma_f32_16x16x32_f16(a0, b, acc[0][ct], 0, 0, 0);
            acc[1][ct] = __builtin_amdgcn_mfma_f32_16x16x32_f16(a1, b, acc[1][ct], 0, 0, 0);
        }
    }
    // C/D: col = l16, row = quad*4 + r
    #pragma unroll
    for (int rt = 0; rt < 2; ++rt) {
        #pragma unroll
        for (int r = 0; r < 4; ++r) {
            int row = rb + w * 32 + rt * 16 + quad * 4 + r;
            if (row < n) {
                float dv = dis[row];
                #pragma unroll
                for (int ct = 0; ct < 8; ++ct)
                    Y[(size_t)row * D + ct * 16 + l16] = (_Float16)(acc[rt][ct][r] * dv);
            }
        }
    }
}

// Layer 1: fp32 x input, converted to fp16 during LDS staging; otherwise identical.
__global__ __launch_bounds__(256) void gemm_mfma_x(const float* __restrict__ X,
                                                   const _Float16* __restrict__ Wt,  // [n][k]
                                                   const float* __restrict__ dis,
                                                   _Float16* __restrict__ Y, int n) {
    __shared__ _Float16 sA[128 * PADK];
    __shared__ _Float16 sB[128 * PADK];
    int t = threadIdx.x;
    int rb = blockIdx.x * 128;
    int rows = min(128, n - rb);

    for (int i = t; i < 128 * 16; i += 256) {
        int r = i >> 4, s = i & 15;
        *(uint4*)&sB[r * PADK + s * 8] = ((const uint4*)Wt)[i];
    }
    for (int i = t; i < rows * 16; i += 256) {
        int r = i >> 4, s = i & 15;
        const float* xp = X + (size_t)(rb + r) * D + s * 8;
        float4 a = *(const float4*)xp;
        float4 b = *(const float4*)(xp + 4);
        _Float16 h[8] = {(_Float16)a.x, (_Float16)a.y, (_Float16)a.z, (_Float16)a.w,
                         (_Float16)b.x, (_Float16)b.y, (_Float16)b.z, (_Float16)b.w};
        *(half8*)&sA[r * PADK + s * 8] = *(half8*)h;
    }
    if (rows < 128) {
        for (int i = rows * 16 + t; i < 128 * 16; i += 256) {
            int r = i >> 4, s = i & 15;
            *(uint4*)&sA[r * PADK + s * 8] = make_uint4(0, 0, 0, 0);
        }
    }
    __syncthreads();

    int w = t >> 6, lane = t & 63;
    int quad = lane >> 4, l16 = lane & 15;
    float4v acc[2][8];
    #pragma unroll
    for (int rt = 0; rt < 2; ++rt)
        #pragma unroll
        for (int ct = 0; ct < 8; ++ct)
            acc[rt][ct] = (float4v){0.f, 0.f, 0.f, 0.f};

    #pragma unroll
    for (int k0 = 0; k0 < 128; k0 += 32) {
        half8 a0 = *(half8*)&sA[(w * 32 + l16) * PADK + k0 + quad * 8];
        half8 a1 = *(half8*)&sA[(w * 32 + 16 + l16) * PADK + k0 + quad * 8];
        #pragma unroll
        for (int ct = 0; ct < 8; ++ct) {
            half8 b = *(half8*)&sB[(ct * 16 + l16) * PADK + k0 + quad * 8];
            acc[0][ct] = __builtin_amdgcn_mfma_f32_16x16x32_f16(a0, b, acc[0][ct], 0, 0, 0);
            acc[1][ct] = __builtin_amdgcn_mfma_f32_16x16x32_f16(a1, b, acc[1][ct], 0, 0, 0);
        }
    }
    #pragma unroll
    for (int rt = 0; rt < 2; ++rt) {
        #pragma unroll
        for (int r = 0; r < 4; ++r) {
            int row = rb + w * 32 + rt * 16 + quad * 4 + r;
            if (row < n) {
                float dv = dis[row];
                #pragma unroll
                for (int ct = 0; ct < 8; ++ct)
                    Y[(size_t)row * D + ct * 16 + l16] = (_Float16)(acc[rt][ct][r] * dv);
            }
        }
    }
}

// out[v,:] = maybe_relu( dis[v] * (sum_e g[src_e,:] + g[v,:]) + bias )
// g fp16; one node per quarter-wave (16 lanes x uint4 = 256B row).
__global__ __launch_bounds__(256) void aggregate(const __half* __restrict__ g,
                                                 const int* __restrict__ rs,
                                                 const unsigned short* __restrict__ csr,
                                                 const float* __restrict__ dis,
                                                 const float* __restrict__ bias,
                                                 float* __restrict__ outf,
                                                 _Float16* __restrict__ outh,
                                                 int n, int do_relu, int write_half) {
    int v = blockIdx.x * 16 + (threadIdx.x >> 4);
    if (v >= n) return;
    int l16 = threadIdx.x & 15;
    const uint4* g4 = (const uint4*)g;  // 16 uint4 per row
    float acc[8];
    {
        uint4 raw = g4[(size_t)v * 16 + l16];  // self loop (g pre-scaled by dis)
        float2 f0 = __half22float2(*(__half2*)&raw.x);
        float2 f1 = __half22float2(*(__half2*)&raw.y);
        float2 f2 = __half22float2(*(__half2*)&raw.z);
        float2 f3 = __half22float2(*(__half2*)&raw.w);
        acc[0] = f0.x; acc[1] = f0.y; acc[2] = f1.x; acc[3] = f1.y;
        acc[4] = f2.x; acc[5] = f2.y; acc[6] = f3.x; acc[7] = f3.y;
    }
    int e = rs[v], end = rs[v + 1];
    while (e < end) {
        int m = min(16, end - e);
        int sid = (e + l16 < end) ? (int)csr[e + l16] : 0;
        int j = 0;
        for (; j + 7 < m; j += 8) {
            uint4 raw[8];
            #pragma unroll
            for (int u = 0; u < 8; ++u) {
                int s = __shfl(sid, j + u, 16);
                raw[u] = g4[(size_t)s * 16 + l16];
            }
            #pragma unroll
            for (int u = 0; u < 8; ++u) {
                float2 f0 = __half22float2(*(__half2*)&raw[u].x);
                float2 f1 = __half22float2(*(__half2*)&raw[u].y);
                float2 f2 = __half22float2(*(__half2*)&raw[u].z);
                float2 f3 = __half22float2(*(__half2*)&raw[u].w);
                acc[0] += f0.x; acc[1] += f0.y; acc[2] += f1.x; acc[3] += f1.y;
                acc[4] += f2.x; acc[5] += f2.y; acc[6] += f3.x; acc[7] += f3.y;
            }
        }
        for (; j + 3 < m; j += 4) {
            uint4 raw[4];
            #pragma unroll
            for (int u = 0; u < 4; ++u) {
                int s = __shfl(sid, j + u, 16);
                raw[u] = g4[(size_t)s * 16 + l16];
            }
            #pragma unroll
            for (int u = 0; u < 4; ++u) {
                float2 f0 = __half22float2(*(__half2*)&raw[u].x);
                float2 f1 = __half22float2(*(__half2*)&raw[u].y);
                float2 f2 = __half22float2(*(__half2*)&raw[u].z);
                float2 f3 = __half22float2(*(__half2*)&raw[u].w);
                acc[0] += f0.x; acc[1] += f0.y; acc[2] += f1.x; acc[3] += f1.y;
                acc[4] += f2.x; acc[5] += f2.y; acc[6] += f3.x; acc[7] += f3.y;
            }
        }
        for (; j < m; ++j) {
            int s = __shfl(sid, j, 16);
            uint4 raw = g4[(size_t)s * 16 + l16];
            float2 f0 = __half22float2(*(__half2*)&raw.x);
            float2 f1 = __half22float2(*(__half2*)&raw.y);
            float2 f2 = __half22float2(*(__half2*)&raw.z);
            float2 f3 = __half22float2(*(__half2*)&raw.w);
            acc[0] += f0.x; acc[1] += f0.y; acc[2] += f1.x; acc[3] += f1.y;
            acc[4] += f2.x; acc[5] += f2.y; acc[6] += f3.x; acc[7] += f3.y;
        }
        e += m;
    }
    float dv = dis[v];
    const float4* b4 = (const float4*)bias;
    float4 ba = b4[2 * l16], bb = b4[2 * l16 + 1];
    float o[8];
    o[0] = dv * acc[0] + ba.x; o[1] = dv * acc[1] + ba.y;
    o[2] = dv * acc[2] + ba.z; o[3] = dv * acc[3] + ba.w;
    o[4] = dv * acc[4] + bb.x; o[5] = dv * acc[5] + bb.y;
    o[6] = dv * acc[6] + bb.z; o[7] = dv * acc[7] + bb.w;
    if (do_relu) {
        #pragma unroll
        for (int i = 0; i < 8; ++i) o[i] = fmaxf(o[i], 0.f);
    }
    if (write_half) {
        __half2 p0 = __floats2half2_rn(o[0], o[1]);
        __half2 p1 = __floats2half2_rn(o[2], o[3]);
        __half2 p2 = __floats2half2_rn(o[4], o[5]);
        __half2 p3 = __floats2half2_rn(o[6], o[7]);
        uint4 pk;
        pk.x = *(unsigned*)&p0; pk.y = *(unsigned*)&p1;
        pk.z = *(unsigned*)&p2; pk.w = *(unsigned*)&p3;
        ((uint4*)outh)[(size_t)v * 16 + l16] = pk;
    } else {
        float4* orow = (float4*)(outf + (size_t)v * D);
        orow[2 * l16] = make_float4(o[0], o[1], o[2], o[3]);
        orow[2 * l16 + 1] = make_float4(o[4], o[5], o[6], o[7]);
    }
}

// ---------------- host launcher ----------------

extern "C" void kernel_launch(void* const* d_in, const int* in_sizes, int n_in,
                              void* d_out, int out_size, void* d_ws, size_t ws_size,
                              hipStream_t stream) {
    const float* x      = (const float*)d_in[0];
    const float* W_role = (const float*)d_in[1];
    const float* b_role = (const float*)d_in[2];
    const float* W2     = (const float*)d_in[3];
    const float* b2     = (const float*)d_in[4];
    const float* W1     = (const float*)d_in[5];
    const float* b1     = (const float*)d_in[6];
    const int*   ein    = (const int*)d_in[7];
    const int*   eir    = (const int*)d_in[8];

    int n  = in_sizes[0] / D;   // 50000
    int En = in_sizes[7] / 2;   // 640000
    int Er = in_sizes[8] / 2;   // 640000
    const int* src_n = ein;
    const int* dst_n = ein + En;
    const int* src_r = eir;
    const int* dst_r = eir + Er;
    float* out = (float*)d_out;

    int NB = (n + BNODES - 1) >> BSH;                    // 391 buckets/graph
    int Emax = En > Er ? En : Er;
    int NC = (Emax + CHUNK - 1) / CHUNK;                 // 157 chunks/graph
    int L  = NB * NC;                                    // 61387 (must be <= 65536)
    int nb_scan = (L + 1023) / 1024;                     // 60 (must be <= 64)

    char* p = (char*)d_ws;
    auto alloc = [&](size_t bytes) { char* r = p; p += (bytes + 255) & ~(size_t)255; return r; };
    __half*         gbuf   = (__half*)alloc((size_t)n * D * sizeof(__half));      // 12.8 MB
    _Float16*       hbuf   = (_Float16*)alloc((size_t)n * D * sizeof(_Float16));  // 12.8 MB
    _Float16*       Wtr    = (_Float16*)alloc((size_t)D * D * sizeof(_Float16));
    _Float16*       Wt2    = (_Float16*)alloc((size_t)D * D * sizeof(_Float16));
    _Float16*       Wt1    = (_Float16*)alloc((size_t)D * D * sizeof(_Float16));
    float*          dis2   = (float*)alloc((size_t)2 * n * sizeof(float));
    int*            rs2    = (int*)alloc((size_t)2 * (n + 1) * sizeof(int));
    int*            base2  = (int*)alloc((size_t)2 * L * sizeof(int));
    int*            bsum2  = (int*)alloc(512);
    unsigned int*   part_n = (unsigned int*)alloc((size_t)En * sizeof(unsigned int));
    unsigned int*   part_r = (unsigned int*)alloc((size_t)Er * sizeof(unsigned int));
    unsigned short* csr    = (unsigned short*)alloc((size_t)(En + Er) * sizeof(unsigned short));
    float* dis_n = dis2;
    float* dis_r = dis2 + n;
    int*   rs_n  = rs2;
    int*   rs_r  = rs2 + (n + 1);
    unsigned short* csr_n = csr;
    unsigned short* csr_r = csr + En;

    // ---- graph preprocessing: (wprep+hist) -> scan(2 passes) -> partition -> bucket CSR ----
    p1_hist<<<2 * NC, 256, 0, stream>>>(dst_n, dst_r, En, Er,
                                        W_role, W2, W1, Wtr, Wt2, Wt1,
                                        base2, NB, NC, L);
    scan_pass1<<<2 * nb_scan, 1024, 0, stream>>>(base2, bsum2, L, nb_scan);
    scan_pass3<<<2 * nb_scan, 1024, 0, stream>>>(base2, bsum2, L, nb_scan);
    p2_scatter<<<2 * NC, 256, 0, stream>>>(src_n, dst_n, src_r, dst_r, En, Er,
                                           base2, part_n, part_r, NB, NC, L);
    p3_csr<<<2 * NB, 256, 0, stream>>>(part_n, part_r, base2, rs2, dis2,
                                       csr_n, csr_r, n, NB, NC, L, En, Er);

    // ---- 3 GCN layers ----
    int gblk = (n + 127) / 128;
    int ablk = (n + 15) / 16;
    // layer 1: role graph; MFMA GEMM (fp32 x staged->fp16) -> fp16 g; aggregate -> fp16 h
    gemm_mfma_x<<<gblk, 256, 0, stream>>>(x, Wtr, dis_r, (_Float16*)gbuf, n);
    aggregate<<<ablk, 256, 0, stream>>>(gbuf, rs_r, csr_r, dis_r, b_role,
                                        nullptr, hbuf, n, 1, 1);
    // layer 2: normal graph; MFMA GEMM (fp16 in/out); aggregate -> fp16 h
    gemm_mfma<<<gblk, 256, 0, stream>>>(hbuf, Wt2, dis_n, (_Float16*)gbuf, n);
    aggregate<<<ablk, 256, 0, stream>>>(gbuf, rs_n, csr_n, dis_n, b2,
                                        nullptr, hbuf, n, 1, 1);
    // layer 3: normal graph; MFMA GEMM; aggregate -> fp32 d_out
    gemm_mfma<<<gblk, 256, 0, stream>>>(hbuf, Wt1, dis_n, (_Float16*)gbuf, n);
    aggregate<<<ablk, 256, 0, stream>>>(gbuf, rs_n, csr_n, dis_n, b1,
                                        out, nullptr, n, 0, 0);
}